// Round 8
// baseline (504.584 us; speedup 1.0000x reference)
//
#include <hip/hip_runtime.h>
#include <cmath>
#include <cstdint>

typedef __bf16 bf16;
typedef __bf16 bf16x8 __attribute__((ext_vector_type(8)));
typedef __bf16 bf16x4 __attribute__((ext_vector_type(4)));
typedef float f32x4 __attribute__((ext_vector_type(4)));

#define CEXP 0.1803368852f   // 0.125 / ln(2)

// ---------------- async global->LDS (width 16) ----------------
__device__ __forceinline__ void async_ld16(const void* g, void* l) {
  __builtin_amdgcn_global_load_lds(
      (__attribute__((address_space(1))) void*)(uintptr_t)g,
      (__attribute__((address_space(3))) void*)l, 16, 0, 0);
}

// ---------------- fused fp32 -> bf16 cast of all 7 tensors ----------------
__global__ __launch_bounds__(256) void cast_all(
    const float* __restrict__ x,  const float* __restrict__ wq, const float* __restrict__ wk,
    const float* __restrict__ wv, const float* __restrict__ wo, const float* __restrict__ w1,
    const float* __restrict__ w2,
    bf16* xb, bf16* wqb, bf16* wkb, bf16* wvb, bf16* wob, bf16* w1b, bf16* w2b)
{
  int i = blockIdx.x * 256 + threadIdx.x;
  const int M1 = 1 << 20, Q = 1 << 18;
  const float* src; bf16* dst; int off;
  if      (i < M1)            { src = x;  dst = xb;  off = i; }
  else if (i < M1 + Q)        { src = wq; dst = wqb; off = i - M1; }
  else if (i < M1 + 2 * Q)    { src = wk; dst = wkb; off = i - M1 - Q; }
  else if (i < M1 + 3 * Q)    { src = wv; dst = wvb; off = i - M1 - 2 * Q; }
  else if (i < M1 + 4 * Q)    { src = wo; dst = wob; off = i - M1 - 3 * Q; }
  else if (i < 3 * M1)        { src = w1; dst = w1b; off = i - M1 - 4 * Q; }
  else                        { src = w2; dst = w2b; off = i - 3 * M1; }
  float4 v = ((const float4*)src)[off];
  bf16x4 o; o[0]=(bf16)v.x; o[1]=(bf16)v.y; o[2]=(bf16)v.z; o[3]=(bf16)v.w;
  ((bf16x4*)dst)[off] = o;
}

// ------- GEMM core, LDS double-buffered, ONE barrier per BK=32 iteration -------
// vtrans: write outB as V^T layout [(b*16+h)*64+d][1024] (for QKV's V output).
template<int BM>
__device__ __forceinline__ void gemm_core(
    const bf16* __restrict__ A, const bf16* __restrict__ Bm, const float* __restrict__ bias,
    float* __restrict__ outF, bf16* __restrict__ outB,
    const float* __restrict__ residF, const bf16* __restrict__ residB,
    int N, int kld, int kbeg, int kend, int relu, int vtrans, bf16* As, bf16* Bs)
{
  constexpr int MI = BM / 32;
  const int tid  = threadIdx.x;
  const int wave = tid >> 6, lane = tid & 63;
  const int lr = lane & 15, lq = lane >> 4;
  const int bm = blockIdx.x * BM, bn = blockIdx.y * 128;
  const int wm = (wave >> 1) * (BM / 2), wn = (wave & 1) * 64;
  const int srow = lane >> 2, scol = (lane & 3) * 8;

  const f32x4 fz = {0.f, 0.f, 0.f, 0.f};
  f32x4 acc[MI][4];
#pragma unroll
  for (int i = 0; i < MI; i++)
#pragma unroll
    for (int j = 0; j < 4; j++) acc[i][j] = fz;

  auto issue = [&](int k0, int buf) {
    bf16* Ad = As + buf * (BM * 32);
    bf16* Bd = Bs + buf * (128 * 32);
    if (BM == 128) {
#pragma unroll
      for (int cc = 0; cc < 2; ++cc) {
        int c = wave * 2 + cc;
        async_ld16(A + (size_t)(bm + c * 16 + srow) * kld + k0 + scol, Ad + c * 512);
      }
    } else {
      async_ld16(A + (size_t)(bm + wave * 16 + srow) * kld + k0 + scol, Ad + wave * 512);
    }
#pragma unroll
    for (int cc = 0; cc < 2; ++cc) {
      int c = wave * 2 + cc;
      async_ld16(Bm + (size_t)(bn + c * 16 + srow) * kld + k0 + scol, Bd + c * 512);
    }
  };

  const int nit = (kend - kbeg) >> 5;
  issue(kbeg, 0);
  for (int i = 0; i < nit; i++) {
    __syncthreads();
    if (i + 1 < nit) issue(kbeg + (i + 1) * 32, (i + 1) & 1);
    const bf16* Ab = As + (i & 1) * (BM * 32);
    const bf16* Bb = Bs + (i & 1) * (128 * 32);
    bf16x8 af[MI], bfr[4];
#pragma unroll
    for (int mi = 0; mi < MI; mi++) af[mi]  = *(const bf16x8*)(Ab + (wm + mi*16 + lr)*32 + lq*8);
#pragma unroll
    for (int ni = 0; ni < 4; ni++) bfr[ni] = *(const bf16x8*)(Bb + (wn + ni*16 + lr)*32 + lq*8);
#pragma unroll
    for (int mi = 0; mi < MI; mi++)
#pragma unroll
      for (int ni = 0; ni < 4; ni++)
        acc[mi][ni] = __builtin_amdgcn_mfma_f32_16x16x32_bf16(af[mi], bfr[ni], acc[mi][ni], 0, 0, 0);
  }

  if (vtrans) {
#pragma unroll
    for (int ni = 0; ni < 4; ni++) {
      int n = bn + wn + ni*16 + lr;
      float bv = bias ? bias[n] : 0.0f;
      int hh = n >> 6, dd = n & 63;
#pragma unroll
      for (int mi = 0; mi < MI; mi++) {
        int m0 = bm + wm + mi*16 + lq*4;
        int bb = m0 >> 10, s = m0 & 1023;
        bf16x4 o;
#pragma unroll
        for (int r = 0; r < 4; r++) o[r] = (bf16)(acc[mi][ni][r] + bv);
        *(bf16x4*)(outB + ((size_t)((bb * 16 + hh) * 64 + dd)) * 1024 + s) = o;
      }
    }
    return;
  }
#pragma unroll
  for (int ni = 0; ni < 4; ni++) {
    int n = bn + wn + ni*16 + lr;
    float bv = bias ? bias[n] : 0.0f;
#pragma unroll
    for (int mi = 0; mi < MI; mi++) {
#pragma unroll
      for (int r = 0; r < 4; r++) {
        int m = bm + wm + mi*16 + lq*4 + r;
        size_t idx = (size_t)m * N + n;
        float v = acc[mi][ni][r] + bv;
        if (relu) v = fmaxf(v, 0.0f);
        if (residF) v += residF[idx];
        if (residB) v += (float)residB[idx];
        if (outF) outF[idx] = v;
        else      outB[idx] = (bf16)v;
      }
    }
  }
}

template<int BM>
__global__ __launch_bounds__(256) void gemm_bt(
    const bf16* A, const bf16* Bm, const float* bias,
    float* outF, bf16* outB, const float* residF, const bf16* residB,
    int N, int K, int relu)
{
  __shared__ bf16 As[2 * BM * 32];
  __shared__ bf16 Bs[2 * 128 * 32];
  gemm_core<BM>(A, Bm, bias, outF, outB, residF, residB, N, K, 0, K, relu, 0, As, Bs);
}

// split-K, bf16 partials: blockIdx.z = K-chunk; partial z at part + z*4M elems
__global__ __launch_bounds__(256) void gemm_splitk(
    const bf16* A, const bf16* Bm, bf16* part, int N, int kld, int kchunk)
{
  __shared__ bf16 As[2 * 128 * 32];
  __shared__ bf16 Bs[2 * 128 * 32];
  const int z = blockIdx.z;
  gemm_core<128>(A, Bm, nullptr, nullptr, part + (size_t)z * 4194304, nullptr, nullptr,
                 N, kld, z * kchunk, (z + 1) * kchunk, 0, 0, As, Bs);
}

__global__ __launch_bounds__(256) void gemm_qkv(
    const bf16* A, const bf16* Bq, const bf16* Bk, const bf16* Bv,
    const float* bq, const float* bk, const float* bv,
    bf16* Oq, bf16* Ok, bf16* Ovt, int N, int K)
{
  __shared__ bf16 As[2 * 128 * 32];
  __shared__ bf16 Bs[2 * 128 * 32];
  const int z = blockIdx.z;
  const bf16* Bm  = z == 0 ? Bq : (z == 1 ? Bk : Bv);
  const float* bi = z == 0 ? bq : (z == 1 ? bk : bv);
  bf16* O         = z == 0 ? Oq : (z == 1 ? Ok : Ovt);
  gemm_core<128>(A, Bm, bi, nullptr, O, nullptr, nullptr, N, K, 0, K, 0, (z == 2), As, Bs);
}

// ------------- flash attention v6b: BARRIER-FREE k-loop, paired-tile PV -------------
// S^T = K.Q^T per wave over its own 16-k slice (K frags from global). S^T's C-layout
// (lane: P[q=lr][k=lq*4+r]) matches the lo/hi halves of the 16x16x32 A-operand layout,
// so TWO consecutive tiles' P/V fragments concatenate into one K=32 MFMA (contraction
// index is just a label — any lane<->k bijection shared by A and B is valid).
// The k-loop has NO __syncthreads and no LDS except write-once hist stores.
#define S_LEN 1024
#define ROWSTR 1024

__global__ __launch_bounds__(256) void attn_kernel(
    const bf16* __restrict__ Qg, const bf16* __restrict__ Kg, const bf16* __restrict__ Vt,
    const float* __restrict__ Wrel, bf16* __restrict__ Og)
{
  __shared__ __align__(16) bf16 hist[64][136];   // 17408 B, raw exp mass, write-once
  __shared__ __align__(16) bf16 rel_s[64][136];  // 17408 B; epilogue: Wr^T [64][136]
  __shared__ __align__(16) float Obuf[64][64];   // 16384 B; preamble: Wst bf16 stage
  __shared__ float lbuf[256];
  __shared__ float hbuf[256];                    // total 53248 B -> 3 blocks/CU

  const int tid = threadIdx.x;
  const int wave = tid >> 6, lane = tid & 63;
  const int lr = lane & 15, lq = lane >> 4;
  const int qblk = 15 - blockIdx.x;              // big-work blocks first
  const int bh = blockIdx.y;
  const int b = bh >> 4, h = bh & 15;
  const int q0 = qblk * 64;
  const int T = qblk + 1;
  const int nearStart = (T > 3) ? T - 3 : 0;
  const size_t rowbase = (size_t)b * S_LEN * ROWSTR + h * 64;
  const size_t vtbase = (size_t)bh * 65536;      // bh*64*1024
  const f32x4 fz = {0.f, 0.f, 0.f, 0.f};

  // ---- preamble: stage Wrel[128..255] packed [t][d] into Obuf region; zero hist ----
  bf16* Wst = (bf16*)Obuf;
  for (int e = tid; e < 128 * 64; e += 256)
    Wst[e] = (bf16)Wrel[(size_t)(128 + (e >> 6)) * 64 + (e & 63)];
  for (int e = tid; e < 64 * 68; e += 256) ((uint*)hist)[e] = 0u;

  // Q fragments: all 64 q-rows per wave (B-operand of S^T)
  bf16x8 qf[4][2];
#pragma unroll
  for (int qt = 0; qt < 4; qt++)
#pragma unroll
    for (int c = 0; c < 2; c++)
      qf[qt][c] = *(const bf16x8*)(Qg + rowbase + (size_t)(q0 + qt*16 + lr) * ROWSTR + c*32 + lq*8);

  // Wrel[256] broadcast A-frag (t=128 column of rel table)
  bf16x8 wb[2];
#pragma unroll
  for (int c = 0; c < 2; c++)
#pragma unroll
    for (int j = 0; j < 8; j++)
      wb[c][j] = (bf16)Wrel[(size_t)256 * 64 + c*32 + lq*8 + j];

  __syncthreads();

  // rel^T[t][q] = Wrel[t+128].Q[q], pre-scaled by CEXP
#pragma unroll
  for (int tt = 0; tt < 2; ++tt)
#pragma unroll
    for (int qt = 0; qt < 4; ++qt) {
      f32x4 a = fz;
#pragma unroll
      for (int c = 0; c < 2; c++) {
        bf16x8 wf = *(const bf16x8*)(Wst + (wave*32 + tt*16 + lr) * 64 + c*32 + lq*8);
        a = __builtin_amdgcn_mfma_f32_16x16x32_bf16(wf, qf[qt][c], a, 0, 0, 0);
      }
      bf16x4 pk; pk[0]=(bf16)(a[0]*CEXP); pk[1]=(bf16)(a[1]*CEXP);
                 pk[2]=(bf16)(a[2]*CEXP); pk[3]=(bf16)(a[3]*CEXP);
      *(bf16x4*)(&rel_s[qt*16 + lr][wave*32 + tt*16 + lq*4]) = pk;
    }
  {  // t = 128 column
    f32x4 a = fz;
#pragma unroll
    for (int c = 0; c < 2; c++)
      a = __builtin_amdgcn_mfma_f32_16x16x32_bf16(wb[c], qf[wave][c], a, 0, 0, 0);
    if (lq == 0) rel_s[wave*16 + lr][128] = (bf16)(a[0]*CEXP);
  }
  __syncthreads();                               // rel_s visible; Wst reads done

  float relc[4];
#pragma unroll
  for (int qt = 0; qt < 4; qt++) relc[qt] = (float)rel_s[qt*16 + lr][128];
  for (int e = tid; e < 4096; e += 256) ((float*)Obuf)[e] = 0.0f;
  __syncthreads();                               // Obuf zeroed before any ds_add

  float l_p[4] = {0.f,0.f,0.f,0.f}, h_p[4] = {0.f,0.f,0.f,0.f};
  f32x4 acc[4][4];
#pragma unroll
  for (int qt = 0; qt < 4; qt++)
#pragma unroll
    for (int dt = 0; dt < 4; dt++) acc[qt][dt] = fz;

  const int krow = 16*wave + lr;                 // K A-frag row in tile (wave's k-slice)
  const int kcol = 16*wave + lq*4;               // within-tile k for V^T B-frags
  bf16x8 kf0, kf1, kn0, kn1;
  {
    const bf16* kp = Kg + rowbase + (size_t)krow * ROWSTR + lq*8;
    kf0 = *(const bf16x8*)kp; kf1 = *(const bf16x8*)(kp + 32);
  }

  bf16x4 pfb[4], vfb[4];                         // buffered even-tile fragments
  int phase = 0;

  for (int kt = 0; kt < T; ++kt) {
    const int k0 = kt * 64;

    // S^T[k][q] over wave's 16-k slice
    f32x4 sc[4];
#pragma unroll
    for (int qt = 0; qt < 4; qt++) {
      sc[qt] = __builtin_amdgcn_mfma_f32_16x16x32_bf16(kf0, qf[qt][0], fz, 0, 0, 0);
      sc[qt] = __builtin_amdgcn_mfma_f32_16x16x32_bf16(kf1, qf[qt][1], sc[qt], 0, 0, 0);
    }
    // V^T B-frags for THIS tile
    bf16x4 vf[4];
#pragma unroll
    for (int dt = 0; dt < 4; dt++)
      vf[dt] = *(const bf16x4*)(Vt + vtbase + (size_t)(dt*16 + lr) * 1024 + k0 + kcol);
    // prefetch next K frags
    if (kt + 1 < T) {
      const bf16* kp = Kg + rowbase + (size_t)(k0 + 64 + krow) * ROWSTR + lq*8;
      kn0 = *(const bf16x8*)kp; kn1 = *(const bf16x8*)(kp + 32);
    }

    // softmax (m=0, exp2 domain) -> P fragments
    bf16x4 pf[4];
    if (kt < nearStart) {            // far tile: all valid, t>=128 everywhere
#pragma unroll
      for (int qt = 0; qt < 4; qt++) {
        float p0 = exp2f(fmaf(sc[qt][0], CEXP, relc[qt]));
        float p1 = exp2f(fmaf(sc[qt][1], CEXP, relc[qt]));
        float p2 = exp2f(fmaf(sc[qt][2], CEXP, relc[qt]));
        float p3 = exp2f(fmaf(sc[qt][3], CEXP, relc[qt]));
        float s4 = p0 + p1 + p2 + p3;
        l_p[qt] += s4; h_p[qt] += s4;
        pf[qt][0]=(bf16)p0; pf[qt][1]=(bf16)p1; pf[qt][2]=(bf16)p2; pf[qt][3]=(bf16)p3;
      }
    } else {                         // near tile: mask + per-distance bias
#pragma unroll
      for (int qt = 0; qt < 4; qt++) {
        int qg = q0 + qt*16 + lr;
#pragma unroll
        for (int r = 0; r < 4; r++) {
          int kg = k0 + 16*wave + lq*4 + r;
          float p = 0.0f;
          if (kg <= qg) {
            int t = qg - kg; int tc = t > 128 ? 128 : t;
            p = exp2f(fmaf(sc[qt][r], CEXP, (float)rel_s[qt*16 + lr][tc]));
            l_p[qt] += p;
            if (t >= 128) h_p[qt] += p;
            else          hist[qt*16 + lr][t] = (bf16)p;
          }
          pf[qt][r] = (bf16)p;
        }
      }
    }

    // paired-tile PV: buffer even tile; on odd tile fuse both into K=32 MFMA
    if (phase == 0) {
#pragma unroll
      for (int qt = 0; qt < 4; qt++) pfb[qt] = pf[qt];
#pragma unroll
      for (int dt = 0; dt < 4; dt++) vfb[dt] = vf[dt];
      phase = 1;
    } else {
#pragma unroll
      for (int qt = 0; qt < 4; qt++) {
        bf16x8 p8 = __builtin_shufflevector(pfb[qt], pf[qt], 0,1,2,3,4,5,6,7);
#pragma unroll
        for (int dt = 0; dt < 4; dt++) {
          bf16x8 v8 = __builtin_shufflevector(vfb[dt], vf[dt], 0,1,2,3,4,5,6,7);
          acc[qt][dt] = __builtin_amdgcn_mfma_f32_16x16x32_bf16(p8, v8, acc[qt][dt], 0, 0, 0);
        }
      }
      phase = 0;
    }

    kf0 = kn0; kf1 = kn1;
  }
  if (phase) {                        // odd T tail: hi half zero-P
    const bf16x4 z4 = {};
#pragma unroll
    for (int qt = 0; qt < 4; qt++) {
      bf16x8 p8 = __builtin_shufflevector(pfb[qt], z4, 0,1,2,3,4,5,6,7);
#pragma unroll
      for (int dt = 0; dt < 4; dt++) {
        bf16x8 v8 = __builtin_shufflevector(vfb[dt], z4, 0,1,2,3,4,5,6,7);
        acc[qt][dt] = __builtin_amdgcn_mfma_f32_16x16x32_bf16(p8, v8, acc[qt][dt], 0, 0, 0);
      }
    }
  }

  // ---- epilogue ----
#pragma unroll
  for (int qt = 0; qt < 4; qt++) {
    l_p[qt] += __shfl_xor(l_p[qt], 16); l_p[qt] += __shfl_xor(l_p[qt], 32);
    h_p[qt] += __shfl_xor(h_p[qt], 16); h_p[qt] += __shfl_xor(h_p[qt], 32);
  }
  __syncthreads();                     // all waves done with loop (rel_s/hist stable)

  // reduce per-wave O partials into Obuf
#pragma unroll
  for (int qt = 0; qt < 4; qt++)
#pragma unroll
    for (int dt = 0; dt < 4; dt++)
#pragma unroll
      for (int r = 0; r < 4; r++)
        atomicAdd(&Obuf[qt*16 + lq*4 + r][dt*16 + lr], acc[qt][dt][r]);
  if (lq == 0) {
#pragma unroll
    for (int qt = 0; qt < 4; qt++) {
      lbuf[wave*64 + qt*16 + lr] = l_p[qt];
      hbuf[wave*64 + qt*16 + lr] = h_p[qt];
    }
  }
  bf16* Wr_t = &rel_s[0][0];           // overwrite rel table with Wr^T [d][t]
  for (int e = tid; e < 64 * 128; e += 256) {
    int d = e >> 7, t = e & 127;
    Wr_t[d * 136 + t] = (bf16)Wrel[(size_t)(128 + t) * 64 + d];
  }
  __syncthreads();

  f32x4 acc_o[4];
#pragma unroll
  for (int dt = 0; dt < 4; dt++)
#pragma unroll
    for (int r = 0; r < 4; r++)
      acc_o[dt][r] = Obuf[wave*16 + lq*4 + r][dt*16 + lr];

#pragma unroll
  for (int c = 0; c < 4; c++) {        // out += hist @ Wrel[t<128]
    bf16x8 hf = *(const bf16x8*)&hist[wave*16 + lr][c*32 + lq*8];
#pragma unroll
    for (int dt = 0; dt < 4; dt++) {
      bf16x8 wf = *(const bf16x8*)(Wr_t + (dt*16 + lr) * 136 + c*32 + lq*8);
      acc_o[dt] = __builtin_amdgcn_mfma_f32_16x16x32_bf16(hf, wf, acc_o[dt], 0, 0, 0);
    }
  }
  float l4[4], h4[4];
#pragma unroll
  for (int r = 0; r < 4; r++) {
    int q = wave*16 + lq*4 + r;
    l4[r] = lbuf[q] + lbuf[64+q] + lbuf[128+q] + lbuf[192+q];
    h4[r] = hbuf[q] + hbuf[64+q] + hbuf[128+q] + hbuf[192+q];
  }
#pragma unroll
  for (int dt = 0; dt < 4; dt++) {
    float wv = Wrel[(size_t)256 * 64 + dt*16 + lr];
#pragma unroll
    for (int r = 0; r < 4; r++) acc_o[dt][r] += h4[r] * wv;
  }
#pragma unroll
  for (int dt = 0; dt < 4; dt++)
#pragma unroll
    for (int r = 0; r < 4; r++) {
      int qg = q0 + wave*16 + lq*4 + r;
      Og[rowbase + (size_t)qg * ROWSTR + dt*16 + lr] = (bf16)(acc_o[dt][r] / l4[r]);
    }
}

// ------- fused split-K reduce (bf16 partials) + bias + residual + LayerNorm -------
__global__ __launch_bounds__(256) void ln_fuseB(
    const bf16* __restrict__ parts, int np,
    const float* __restrict__ bias,
    const float* __restrict__ residF, const bf16* __restrict__ residB,
    const float* __restrict__ alpha, const float* __restrict__ beta,
    float* __restrict__ outF, bf16* __restrict__ outB)
{
  const int row = blockIdx.x, tid = threadIdx.x;
  const int lane = tid & 63, wave = tid >> 6;
  const size_t base = (size_t)row * 1024 + tid * 4;
  float4 v = {0.f, 0.f, 0.f, 0.f};
  for (int p = 0; p < np; p++) {
    bf16x4 pv = *(const bf16x4*)(parts + (size_t)p * 4194304 + base);
    v.x += (float)pv[0]; v.y += (float)pv[1]; v.z += (float)pv[2]; v.w += (float)pv[3];
  }
  float4 bv = ((const float4*)bias)[tid];
  v.x += bv.x; v.y += bv.y; v.z += bv.z; v.w += bv.w;
  if (residF) {
    float4 rv = *(const float4*)(residF + base);
    v.x += rv.x; v.y += rv.y; v.z += rv.z; v.w += rv.w;
  }
  if (residB) {
    bf16x4 rv = *(const bf16x4*)(residB + base);
    v.x += (float)rv[0]; v.y += (float)rv[1]; v.z += (float)rv[2]; v.w += (float)rv[3];
  }
  float s  = v.x + v.y + v.z + v.w;
  float ss = v.x*v.x + v.y*v.y + v.z*v.z + v.w*v.w;
#pragma unroll
  for (int off = 32; off; off >>= 1) { s += __shfl_down(s, off); ss += __shfl_down(ss, off); }
  __shared__ float rs[4], rss[4];
  if (lane == 0) { rs[wave] = s; rss[wave] = ss; }
  __syncthreads();
  s  = rs[0] + rs[1] + rs[2] + rs[3];
  ss = rss[0] + rss[1] + rss[2] + rss[3];
  float mean = s * (1.0f / 1024.0f);
  float var  = ss * (1.0f / 1024.0f) - mean * mean;
  float inv  = 1.0f / (sqrtf(fmaxf(var, 0.0f)) + 1e-5f);
  float4 a = ((const float4*)alpha)[tid];
  float4 bb = ((const float4*)beta)[tid];
  float o0 = a.x * (v.x - mean) * inv + bb.x;
  float o1 = a.y * (v.y - mean) * inv + bb.y;
  float o2 = a.z * (v.z - mean) * inv + bb.z;
  float o3 = a.w * (v.w - mean) * inv + bb.w;
  if (outF) { float4 o = {o0, o1, o2, o3}; *(float4*)(outF + base) = o; }
  if (outB) { bf16x4 o; o[0]=(bf16)o0; o[1]=(bf16)o1; o[2]=(bf16)o2; o[3]=(bf16)o3;
              *(bf16x4*)(outB + base) = o; }
}

// ---------------- launcher ----------------
extern "C" void kernel_launch(void* const* d_in, const int* in_sizes, int n_in,
                              void* d_out, int out_size, void* d_ws, size_t ws_size,
                              hipStream_t stream) {
  (void)in_sizes; (void)n_in; (void)out_size; (void)ws_size;
  const int D = 1024, DFF = 4096;

  const float* x    = (const float*)d_in[0];
  const float* Wq   = (const float*)d_in[2];
  const float* bq   = (const float*)d_in[3];
  const float* Wk   = (const float*)d_in[4];
  const float* bk   = (const float*)d_in[5];
  const float* Wv   = (const float*)d_in[6];
  const float* bv   = (const float*)d_in[7];
  const float* Wo   = (const float*)d_in[8];
  const float* bo   = (const float*)d_in[9];
  const float* Wrel = (const float*)d_in[10];
  const float* g1   = (const float*)d_in[11];
  const float* be1  = (const float*)d_in[12];
  const float* g2   = (const float*)d_in[13];
  const float* be2  = (const float*)d_in[14];
  const float* W1   = (const float*)d_in[15];
  const float* b1   = (const float*)d_in[16];
  const float* W2   = (const float*)d_in[17];
  const float* b2   = (const float*)d_in[18];

  char* ws = (char*)d_ws;
  const size_t MB = 1024 * 1024;
  bf16*  xb   = (bf16*)(ws + 0);        // 8 MB; reused as h_bf16 after LN1
  bf16*  Wqb  = (bf16*)(ws + 8  * MB);
  bf16*  Wkb  = (bf16*)(ws + 10 * MB);
  bf16*  Wvb  = (bf16*)(ws + 12 * MB);
  bf16*  Wob  = (bf16*)(ws + 14 * MB);
  bf16*  W1b  = (bf16*)(ws + 16 * MB);  // 8 MB
  bf16*  W2b  = (bf16*)(ws + 24 * MB);  // 8 MB
  bf16*  Qb   = (bf16*)(ws + 32 * MB);  // 8 MB
  bf16*  Kb   = (bf16*)(ws + 40 * MB);
  bf16*  Vt   = (bf16*)(ws + 48 * MB);  // V^T [(b*16+h)*64+d][1024] (written by QKV)
  bf16*  AOb  = (bf16*)(ws + 56 * MB);
  bf16*  partb= (bf16*)(ws + 64 * MB);  // up to 4 x 8 MB bf16 split-K partials
  bf16*  f1   = Qb;                     // 32 MB overlay (Qb..AOb dead by FFN1)
  bf16*  hb   = xb;

  cast_all<<<16384, 256, 0, stream>>>(x, Wq, Wk, Wv, Wo, W1, W2,
                                      xb, Wqb, Wkb, Wvb, Wob, W1b, W2b);

  // QKV (z=2 writes V^T directly via vtrans epilogue)
  gemm_qkv<<<dim3(32, 8, 3), 256, 0, stream>>>(xb, Wqb, Wkb, Wvb, bq, bk, bv, Qb, Kb, Vt, D, D);
  // attention (barrier-free k-loop)
  attn_kernel<<<dim3(16, 64), 256, 0, stream>>>(Qb, Kb, Vt, Wrel, AOb);
  // output projection, split-K=2, bf16 partials
  gemm_splitk<<<dim3(32, 8, 2), 256, 0, stream>>>(AOb, Wob, partb, D, D, 512);
  ln_fuseB<<<4096, 256, 0, stream>>>(partb, 2, bo, x, nullptr, g1, be1, nullptr, hb);
  // FFN1
  gemm_bt<128><<<dim3(32, 32), 256, 0, stream>>>(hb, W1b, b1, nullptr, f1, nullptr, nullptr, DFF, D, 1);
  // FFN2, split-K=4, bf16 partials
  gemm_splitk<<<dim3(32, 8, 4), 256, 0, stream>>>(f1, W2b, partb, D, DFF, 1024);
  ln_fuseB<<<4096, 256, 0, stream>>>(partb, 4, b2, nullptr, hb, g2, be2, (float*)d_out, nullptr);
}